// Round 7
// baseline (378.641 us; speedup 1.0000x reference)
//
#include <hip/hip_runtime.h>
#include <hip/hip_bf16.h>
#include <math.h>

#define NB 4
#define NS 2048
#define NE 768
#define NH 12
#define ND 64
#define NQKV 2304
#define BHN (NB*NH)

typedef __attribute__((ext_vector_type(8))) short bf16x8;
typedef __attribute__((ext_vector_type(4))) float f32x4;
typedef __attribute__((ext_vector_type(16))) float f32x16;
typedef unsigned int uint32;

// Q pre-scale: 1/sqrt(64) * log2(e), folded into gemm1's Q write-out so the
// attention softmax runs in base-2 domain with no per-score multiplies.
#define QSCALE (0.125f * 1.44269504f)

__device__ __forceinline__ ushort f2bf(float x){
  __hip_bfloat16 h = __float2bfloat16(x);
  return *reinterpret_cast<ushort*>(&h);
}
__device__ __forceinline__ float bf2f(ushort u){
  __hip_bfloat16 h = *reinterpret_cast<__hip_bfloat16*>(&u);
  return __bfloat162float(h);
}
__device__ __forceinline__ void split2(float x, ushort &hi, ushort &lo){
  ushort h = f2bf(x);
  hi = h;
  lo = f2bf(x - bf2f(h));
}
__device__ __forceinline__ uint32 cvtpk(float lo, float hi){
  uint32 r;
  asm("v_cvt_pk_bf16_f32 %0, %1, %2" : "=v"(r) : "v"(lo), "v"(hi));
  return r;
}
__device__ __forceinline__ void pl32swap(uint32 &a, uint32 &b){
  asm("v_permlane32_swap_b32 %0, %1" : "+v"(a), "+v"(b));
}
__device__ __forceinline__ void gl_lds16(const void* g, void* l){
  __builtin_amdgcn_global_load_lds(
      (const __attribute__((address_space(1))) unsigned int*)g,
      (__attribute__((address_space(3))) unsigned int*)l, 16, 0, 0);
}

// ---------------------------------------------------------------------------
// X (fp32) -> Xhi, Xlo (bf16), same layout. 8 elems/thread.
// ---------------------------------------------------------------------------
__global__ __launch_bounds__(256)
void k_convert_x(const float* __restrict__ X, ushort* __restrict__ H, ushort* __restrict__ L)
{
  const int idx = (blockIdx.x*256 + threadIdx.x)*8;
  float4 x0 = *(const float4*)(X+idx);
  float4 x1 = *(const float4*)(X+idx+4);
  float xs[8] = {x0.x,x0.y,x0.z,x0.w,x1.x,x1.y,x1.z,x1.w};
  bf16x8 vh, vl;
#pragma unroll
  for (int i=0;i<8;++i){
    ushort hi, lo; split2(xs[i], hi, lo);
    vh[i] = (short)hi; vl[i] = (short)lo;
  }
  *(bf16x8*)(H+idx) = vh;
  *(bf16x8*)(L+idx) = vl;
}

// ---------------------------------------------------------------------------
// W (fp32, K x N row-major) -> Wt hi/lo (bf16, N x K row-major). 64x64 tiles.
// ---------------------------------------------------------------------------
__global__ __launch_bounds__(256)
void k_transpose_w(const float* __restrict__ W, ushort* __restrict__ TH, ushort* __restrict__ TL,
                   int K, int N)
{
  __shared__ ushort LH[64][72], LL[64][72];
  const int tid = threadIdx.x;
  const int k0 = blockIdx.y*64, n0 = blockIdx.x*64;
  const int kk = tid >> 4, nn = (tid & 15)*4;
#pragma unroll
  for (int p=0;p<4;++p){
    const int k = kk + p*16;
    float4 v = *(const float4*)(W + (size_t)(k0+k)*N + n0 + nn);
    float xs[4] = {v.x, v.y, v.z, v.w};
#pragma unroll
    for (int c=0;c<4;++c){
      ushort hi, lo; split2(xs[c], hi, lo);
      LH[nn+c][k] = hi; LL[nn+c][k] = lo;
    }
  }
  __syncthreads();
  const int nr = tid >> 2, ch = (tid & 3)*16;
  bf16x8 h0, h1, l0, l1;
#pragma unroll
  for (int i=0;i<8;++i){
    h0[i] = (short)LH[nr][ch+i];   h1[i] = (short)LH[nr][ch+8+i];
    l0[i] = (short)LL[nr][ch+i];   l1[i] = (short)LL[nr][ch+8+i];
  }
  ushort* dh = TH + (size_t)(n0+nr)*K + k0 + ch;
  ushort* dl = TL + (size_t)(n0+nr)*K + k0 + ch;
  *(bf16x8*)dh = h0; *(bf16x8*)(dh+8) = h1;
  *(bf16x8*)dl = l0; *(bf16x8*)(dl+8) = l1;
}

// ---------------------------------------------------------------------------
// Pack mask bits per (b, kt-tile, half): bit (r + 16*t) = mask[key(r,h,t)]
// key(r,h,t) = (r&3) + 8*(r>>2) + 4*h + 32*t  (matches 32x32 MFMA D rows)
// ---------------------------------------------------------------------------
__global__ __launch_bounds__(256)
void k_maskprep(const int* __restrict__ mask, uint32* __restrict__ MW)
{
  const int tid = threadIdx.x;
  const int b = tid >> 6, kt = (tid >> 1) & 31, h = tid & 1;
  uint32 wv = 0;
#pragma unroll
  for (int t=0;t<2;++t){
#pragma unroll
    for (int r=0;r<16;++r){
      const int key = (r&3) + 8*(r>>2) + 4*h + 32*t;
      if (mask[b*NS + kt*64 + key] != 0) wv |= (1u << (r + 16*t));
    }
  }
  MW[tid] = wv;
}

// ---------------------------------------------------------------------------
// Split-bf16 GEMM via MFMA, global_load_lds staging + XOR-swizzled LDS.
// A: (Ah,Al) MxK bf16 row-major. B: (Bh[,Bl]) NxK row-major (= W^T).
// NT=3: C = Ah*Bh + Ah*Bl + Al*Bh.  NT=2: C = Ah*Bh + Al*Bh.
// LDS tile [128 rows][32 k] linear; 16B chunk c of row r holds global chunk
// c ^ ((r>>1)&3)  (source pre-swizzled, ds_read applies same XOR).
// MODE 0: scatter to Q(scaled by QSCALE)/K bf16 [bh][s][64], V^T [bh][64][s].
// MODE 1: fp32 C row-major.
// ---------------------------------------------------------------------------
template<int MODE, int NT>
__global__ __launch_bounds__(256)
void k_gemm(const ushort* __restrict__ Ah, const ushort* __restrict__ Al,
            const ushort* __restrict__ Bh, const ushort* __restrict__ Bl,
            float* __restrict__ C,
            ushort* __restrict__ Qo, ushort* __restrict__ Ko, ushort* __restrict__ Vo,
            int M, int N, int K)
{
  __shared__ ushort Ash[4096], Asl[4096], Bsh[4096];
  __shared__ ushort Bsl[NT == 3 ? 4096 : 16];
  const int tid = threadIdx.x;
  const int lane = tid & 63;
  const int w = tid >> 6;
  const int wm = w & 1, wn = w >> 1;
  const int l15 = lane & 15, lg = lane >> 4;
  const int m0 = blockIdx.y*128, n0 = blockIdx.x*128;

  f32x4 acc[4][4] = {};

  const int srow   = tid >> 2;   // 0..63 tile row (issue i adds 64)
  const int schunk = tid & 3;    // 16B chunk within row
  const int ldst   = tid*8;      // ushort offset within 64-row half

  for (int k0 = 0; k0 < K; k0 += 32) {
    if (k0) __syncthreads();
#pragma unroll
    for (int i=0;i<2;++i){
      const int row = i*64 + srow;
      const int kc  = (schunk ^ ((row>>1)&3))*8;
      const size_t ao = (size_t)(m0+row)*K + k0 + kc;
      const size_t bo = (size_t)(n0+row)*K + k0 + kc;
      gl_lds16(Ah+ao, &Ash[i*2048+ldst]);
      gl_lds16(Al+ao, &Asl[i*2048+ldst]);
      gl_lds16(Bh+bo, &Bsh[i*2048+ldst]);
      if (NT == 3) gl_lds16(Bl+bo, &Bsl[i*2048+ldst]);
    }
    __syncthreads();

    bf16x8 fah[4], fal[4], fbh[4], fbl[4];
#pragma unroll
    for (int i=0;i<4;++i){
      const int ra = wm*64 + i*16 + l15;
      const int ca = (lg ^ ((ra>>1)&3))*8;
      fah[i] = *(const bf16x8*)&Ash[ra*32 + ca];
      fal[i] = *(const bf16x8*)&Asl[ra*32 + ca];
      const int rb = wn*64 + i*16 + l15;
      const int cb = (lg ^ ((rb>>1)&3))*8;
      fbh[i] = *(const bf16x8*)&Bsh[rb*32 + cb];
      if (NT == 3) fbl[i] = *(const bf16x8*)&Bsl[rb*32 + cb];
    }
    __builtin_amdgcn_s_setprio(1);
#pragma unroll
    for (int mi=0;mi<4;++mi){
#pragma unroll
      for (int ni=0;ni<4;++ni){
        acc[mi][ni] = __builtin_amdgcn_mfma_f32_16x16x32_bf16(fah[mi], fbh[ni], acc[mi][ni], 0,0,0);
        if (NT == 3)
          acc[mi][ni] = __builtin_amdgcn_mfma_f32_16x16x32_bf16(fah[mi], fbl[ni], acc[mi][ni], 0,0,0);
        acc[mi][ni] = __builtin_amdgcn_mfma_f32_16x16x32_bf16(fal[mi], fbh[ni], acc[mi][ni], 0,0,0);
      }
    }
    __builtin_amdgcn_s_setprio(0);
  }

#pragma unroll
  for (int mi=0;mi<4;++mi){
#pragma unroll
    for (int ni=0;ni<4;++ni){
#pragma unroll
      for (int j=0;j<4;++j){
        const int m = m0 + wm*64 + mi*16 + (lane>>4)*4 + j;
        const int n = n0 + wn*64 + ni*16 + l15;
        const float v = acc[mi][ni][j];
        if (MODE == 0) {
          const int bb = m >> 11, ss = m & 2047;
          const int hh = n / 192, rr = n - hh*192;
          const int d = rr & 63;
          if (rr < 64) {
            Qo[((size_t)(bb*NH + hh)*NS + ss)*ND + d] = f2bf(v * QSCALE);
          } else if (rr < 128) {
            Ko[((size_t)(bb*NH + hh)*NS + ss)*ND + d] = f2bf(v);
          } else {
            Vo[((size_t)(bb*NH + hh)*ND + d)*NS + ss] = f2bf(v);  // V^T
          }
        } else {
          C[(size_t)m*N + n] = v;
        }
      }
    }
  }
}

// ---------------------------------------------------------------------------
// Flash attention, swapped-QK^T 32x32x16 MFMA, base-2 online softmax.
// Q pre-scaled by QSCALE at gemm1. Mask folded in as MFMA C-in bias
// (-FLT_MAX), softmax in exp2 domain, skip-rescale when tmax<=m_run (exact).
// ---------------------------------------------------------------------------
__global__ __launch_bounds__(256)
void k_attn(const ushort* __restrict__ Qb, const ushort* __restrict__ Kb,
            const ushort* __restrict__ VTb, const uint32* __restrict__ MW,
            ushort* __restrict__ Ohi, ushort* __restrict__ Olo)
{
  __shared__ ushort Kls[2][4096];  // [buf][64 keys][64 d] swizzled
  __shared__ ushort Vls[2][4096];  // [buf][64 d][64 keys] swizzled

  const int tid = threadIdx.x;
  const int lane = tid & 63;
  const int w = tid >> 6;
  const int l31 = lane & 31;
  const int h = lane >> 5;
  const int qt = blockIdx.x, head = blockIdx.y, b = blockIdx.z;
  const int bh = b*NH + head;
  const int qglob = qt*128 + w*32 + l31;

  bf16x8 qf[4];
  {
    const ushort* qp = Qb + ((size_t)bh*NS + qglob)*ND + h*8;
#pragma unroll
    for (int s=0;s<4;++s) qf[s] = *(const bf16x8*)(qp + s*16);
  }

  const int srow = (w<<3) + (lane>>3);
  const int scol = ((lane&7) ^ (lane>>3)) << 3;
  const ushort* Kg  = Kb  + (size_t)bh*NS*ND;
  const ushort* VTg = VTb + (size_t)bh*ND*NS;
  const int lbase = (w<<9);

#define STAGE(kt_, bsel_)                                                     \
  {                                                                           \
    _Pragma("unroll")                                                         \
    for (int i_=0;i_<2;++i_){                                                 \
      const int row_ = i_*32 + srow;                                          \
      gl_lds16(Kg  + (size_t)((kt_)*64 + row_)*ND + scol,                     \
               &Kls[bsel_][i_*2048 + lbase]);                                 \
      gl_lds16(VTg + (size_t)row_*NS + (kt_)*64 + scol,                       \
               &Vls[bsel_][i_*2048 + lbase]);                                 \
    }                                                                         \
  }

  f32x16 o0, o1;
#pragma unroll
  for (int r=0;r<16;++r){ o0[r]=0.f; o1[r]=0.f; }
  float m_run = -INFINITY, l_run = 0.f;

  STAGE(0, 0);
  __syncthreads();

  for (int kt = 0; kt < NS/64; ++kt){
    const int buf = kt & 1;
    if (kt + 1 < NS/64) STAGE(kt+1, buf^1);
    const uint32 mw = MW[b*64 + kt*2 + h];

    // z init = mask bias: 0 (visible) or -FLT_MAX (masked); QK^T adds on top.
    f32x16 z0, z1;
#pragma unroll
    for (int r=0;r<16;++r){
      const int b0 = ((int)(mw << (31-r))) >> 31;        // 0 or -1
      const int b1 = ((int)(mw << (15-r))) >> 31;        // bit 16+r
      z0[r] = __int_as_float(~b0 & 0xFF7FFFFFu);         // visible->0, masked->-FLT_MAX
      z1[r] = __int_as_float(~b1 & 0xFF7FFFFFu);
    }

    // S^T = K * Q^T (scores already in log2 units: Q pre-scaled)
    const char* kbase = (const char*)&Kls[buf][0];
    __builtin_amdgcn_s_setprio(1);
#pragma unroll
    for (int s=0;s<4;++s){
      const int cb = (s*32 + h*16) ^ ((l31&7)<<4);
      bf16x8 kf0 = *(const bf16x8*)(kbase + l31*128 + cb);
      z0 = __builtin_amdgcn_mfma_f32_32x32x16_bf16(kf0, qf[s], z0, 0,0,0);
      bf16x8 kf1 = *(const bf16x8*)(kbase + (32+l31)*128 + cb);
      z1 = __builtin_amdgcn_mfma_f32_32x32x16_bf16(kf1, qf[s], z1, 0,0,0);
    }
    __builtin_amdgcn_s_setprio(0);

    // online softmax (base-2): tile max over both half-lanes
    float tmax = fmaxf(z0[0], z1[0]);
#pragma unroll
    for (int r=1;r<16;++r) tmax = fmaxf(tmax, fmaxf(z0[r], z1[r]));
    tmax = fmaxf(tmax, __shfl_xor(tmax, 32));

    if (!__all(tmax <= m_run)) {     // skip is exact: alpha would be 2^0 = 1
      const float mnew  = fmaxf(m_run, tmax);
      const float msafe = fmaxf(mnew, -1e30f);
      const float alpha = exp2f(m_run - msafe);
      m_run = mnew;
      l_run *= alpha;
#pragma unroll
      for (int r=0;r<16;++r){ o0[r] *= alpha; o1[r] *= alpha; }
    }
    const float mbase = fmaxf(m_run, -1e30f);

    float sc[32];
    float psum = 0.f;
#pragma unroll
    for (int r=0;r<16;++r){
      const float p0 = exp2f(z0[r] - mbase);
      const float p1 = exp2f(z1[r] - mbase);
      sc[r] = p0; sc[16+r] = p1;
      psum += p0 + p1;
    }
    psum += __shfl_xor(psum, 32);
    l_run += psum;

    // O^T += V^T * P^T ; P-fragments built in-register
    const char* vbase = (const char*)&Vls[buf][0];
#pragma unroll
    for (int ks=0;ks<4;++ks){
      const int rb = (ks&1)*8 + (ks>>1)*16;
      uint32 d0 = cvtpk(sc[rb+0], sc[rb+1]);
      uint32 d2 = cvtpk(sc[rb+4], sc[rb+5]);
      pl32swap(d0, d2);
      uint32 d1 = cvtpk(sc[rb+2], sc[rb+3]);
      uint32 d3 = cvtpk(sc[rb+6], sc[rb+7]);
      pl32swap(d1, d3);
      union { uint32 u[4]; bf16x8 v; } pf;
      pf.u[0] = d0; pf.u[1] = d1; pf.u[2] = d2; pf.u[3] = d3;
      const int cb = (ks*32 + h*16) ^ ((l31&7)<<4);
      __builtin_amdgcn_s_setprio(1);
      bf16x8 vf0 = *(const bf16x8*)(vbase + l31*128 + cb);
      o0 = __builtin_amdgcn_mfma_f32_32x32x16_bf16(vf0, pf.v, o0, 0,0,0);
      bf16x8 vf1 = *(const bf16x8*)(vbase + (32+l31)*128 + cb);
      o1 = __builtin_amdgcn_mfma_f32_32x32x16_bf16(vf1, pf.v, o1, 0,0,0);
      __builtin_amdgcn_s_setprio(0);
    }
    __syncthreads();
  }

  const float inv = 1.f / l_run;
  const size_t obase = ((size_t)(b*NS + qglob))*NE + head*ND;
#pragma unroll
  for (int a=0;a<2;++a){
#pragma unroll
    for (int rp=0;rp<8;++rp){
      const int r = rp*2;
      const float v0 = (a ? o1[r]   : o0[r])   * inv;
      const float v1 = (a ? o1[r+1] : o0[r+1]) * inv;
      ushort h0,lo0,h1,lo1;
      split2(v0, h0, lo0); split2(v1, h1, lo1);
      const int d = (r&3) + 8*(r>>2) + 4*h + 32*a;
      *(uint32*)(Ohi + obase + d) = (uint32)h0 | ((uint32)h1<<16);
      *(uint32*)(Olo + obase + d) = (uint32)lo0 | ((uint32)lo1<<16);
    }
  }
#undef STAGE
}

// ---------------------------------------------------------------------------
extern "C" void kernel_launch(void* const* d_in, const int* in_sizes, int n_in,
                              void* d_out, int out_size, void* d_ws, size_t ws_size,
                              hipStream_t stream)
{
  const float* X    = (const float*)d_in[0];
  const int*   mask = (const int*)d_in[1];
  const float* Wqkv = (const float*)d_in[2];
  const float* Wfc  = (const float*)d_in[3];
  float* out = (float*)d_out;

  char* p = (char*)d_ws;
  const size_t szXE = (size_t)NB*NS*NE;
  const size_t szT  = (size_t)BHN*NS*ND;
  ushort* Xhi = (ushort*)p; p += szXE*2;
  ushort* Xlo = (ushort*)p; p += szXE*2;
  ushort* Wqh = (ushort*)p; p += (size_t)NQKV*NE*2;
  ushort* Wql = (ushort*)p; p += (size_t)NQKV*NE*2;
  ushort* Wfh = (ushort*)p; p += (size_t)NE*NE*2;
  ushort* Wfl = (ushort*)p; p += (size_t)NE*NE*2;
  ushort* Qb  = (ushort*)p; p += szT*2;
  ushort* Kb  = (ushort*)p; p += szT*2;
  ushort* VTb = (ushort*)p; p += szT*2;
  ushort* Ohi = (ushort*)p; p += szXE*2;
  ushort* Olo = (ushort*)p; p += szXE*2;
  uint32* MW  = (uint32*)p; p += 256*4;

  k_convert_x<<<(int)(szXE/2048), 256, 0, stream>>>(X, Xhi, Xlo);
  k_transpose_w<<<dim3(NQKV/64, NE/64), 256, 0, stream>>>(Wqkv, Wqh, Wql, NE, NQKV);
  k_transpose_w<<<dim3(NE/64, NE/64), 256, 0, stream>>>(Wfc, Wfh, Wfl, NE, NE);
  k_maskprep<<<1, 256, 0, stream>>>(mask, MW);
  k_gemm<0,2><<<dim3(NQKV/128, (NB*NS)/128), 256, 0, stream>>>(
      Xhi, Xlo, Wqh, Wql, nullptr, Qb, Kb, VTb, NB*NS, NQKV, NE);
  k_attn<<<dim3(NS/128, NH, NB), 256, 0, stream>>>(Qb, Kb, VTb, MW, Ohi, Olo);
  k_gemm<1,3><<<dim3(NE/128, (NB*NS)/128), 256, 0, stream>>>(
      Ohi, Olo, Wfh, Wfl, out, nullptr, nullptr, nullptr, NB*NS, NE, NE);
}

// Round 12
// 332.925 us; speedup vs baseline: 1.1373x; 1.1373x over previous
//
#include <hip/hip_runtime.h>
#include <hip/hip_bf16.h>
#include <math.h>

#define NB 4
#define NS 2048
#define NE 768
#define NH 12
#define ND 64
#define NQKV 2304
#define BHN (NB*NH)

typedef __attribute__((ext_vector_type(8))) short bf16x8;
typedef __attribute__((ext_vector_type(4))) float f32x4;
typedef __attribute__((ext_vector_type(16))) float f32x16;
typedef unsigned int uint32;

// Q pre-scale: 1/sqrt(64) * log2(e): softmax runs in exp2 domain, no per-score mul.
#define QSCALE (0.125f * 1.44269504f)

__device__ __forceinline__ ushort f2bf(float x){
  __hip_bfloat16 h = __float2bfloat16(x);
  return *reinterpret_cast<ushort*>(&h);
}
__device__ __forceinline__ float bf2f(ushort u){
  __hip_bfloat16 h = *reinterpret_cast<__hip_bfloat16*>(&u);
  return __bfloat162float(h);
}
__device__ __forceinline__ void split2(float x, ushort &hi, ushort &lo){
  ushort h = f2bf(x);
  hi = h;
  lo = f2bf(x - bf2f(h));
}
__device__ __forceinline__ uint32 cvtpk(float lo, float hi){
  uint32 r;
  asm("v_cvt_pk_bf16_f32 %0, %1, %2" : "=v"(r) : "v"(lo), "v"(hi));
  return r;
}
__device__ __forceinline__ void pl32swap(uint32 &a, uint32 &b){
  asm("v_permlane32_swap_b32 %0, %1" : "+v"(a), "+v"(b));
}
// single-instruction exp2 with compiler hazard handling (NOT raw inline asm:
// round-8 showed the raw-asm version races the transcendental wait slot)
__device__ __forceinline__ float exp2x(float x){
#if __has_builtin(__builtin_amdgcn_exp2f)
  return __builtin_amdgcn_exp2f(x);
#else
  return exp2f(x);
#endif
}
__device__ __forceinline__ void gl_lds16(const void* g, void* l){
  __builtin_amdgcn_global_load_lds(
      (const __attribute__((address_space(1))) unsigned int*)g,
      (__attribute__((address_space(3))) unsigned int*)l, 16, 0, 0);
}

// ---------------------------------------------------------------------------
// X (fp32) -> Xhi, Xlo (bf16), same layout. 8 elems/thread.
// ---------------------------------------------------------------------------
__global__ __launch_bounds__(256)
void k_convert_x(const float* __restrict__ X, ushort* __restrict__ H, ushort* __restrict__ L)
{
  const int idx = (blockIdx.x*256 + threadIdx.x)*8;
  float4 x0 = *(const float4*)(X+idx);
  float4 x1 = *(const float4*)(X+idx+4);
  float xs[8] = {x0.x,x0.y,x0.z,x0.w,x1.x,x1.y,x1.z,x1.w};
  bf16x8 vh, vl;
#pragma unroll
  for (int i=0;i<8;++i){
    ushort hi, lo; split2(xs[i], hi, lo);
    vh[i] = (short)hi; vl[i] = (short)lo;
  }
  *(bf16x8*)(H+idx) = vh;
  *(bf16x8*)(L+idx) = vl;
}

// ---------------------------------------------------------------------------
// W (fp32, K x N row-major) -> Wt hi/lo (bf16, N x K row-major). 64x64 tiles.
// ---------------------------------------------------------------------------
__global__ __launch_bounds__(256)
void k_transpose_w(const float* __restrict__ W, ushort* __restrict__ TH, ushort* __restrict__ TL,
                   int K, int N)
{
  __shared__ ushort LH[64][72], LL[64][72];
  const int tid = threadIdx.x;
  const int k0 = blockIdx.y*64, n0 = blockIdx.x*64;
  const int kk = tid >> 4, nn = (tid & 15)*4;
#pragma unroll
  for (int p=0;p<4;++p){
    const int k = kk + p*16;
    float4 v = *(const float4*)(W + (size_t)(k0+k)*N + n0 + nn);
    float xs[4] = {v.x, v.y, v.z, v.w};
#pragma unroll
    for (int c=0;c<4;++c){
      ushort hi, lo; split2(xs[c], hi, lo);
      LH[nn+c][k] = hi; LL[nn+c][k] = lo;
    }
  }
  __syncthreads();
  const int nr = tid >> 2, ch = (tid & 3)*16;
  bf16x8 h0, h1, l0, l1;
#pragma unroll
  for (int i=0;i<8;++i){
    h0[i] = (short)LH[nr][ch+i];   h1[i] = (short)LH[nr][ch+8+i];
    l0[i] = (short)LL[nr][ch+i];   l1[i] = (short)LL[nr][ch+8+i];
  }
  ushort* dh = TH + (size_t)(n0+nr)*K + k0 + ch;
  ushort* dl = TL + (size_t)(n0+nr)*K + k0 + ch;
  *(bf16x8*)dh = h0; *(bf16x8*)(dh+8) = h1;
  *(bf16x8*)dl = l0; *(bf16x8*)(dl+8) = l1;
}

// ---------------------------------------------------------------------------
// Pack mask bits per (b, kt-tile, half): bit (r + 16*t) = mask[key(r,h,t)]
// key(r,h,t) = (r&3) + 8*(r>>2) + 4*h + 32*t  (matches 32x32 MFMA D rows)
// ---------------------------------------------------------------------------
__global__ __launch_bounds__(256)
void k_maskprep(const int* __restrict__ mask, uint32* __restrict__ MW)
{
  const int tid = threadIdx.x;
  const int b = tid >> 6, kt = (tid >> 1) & 31, h = tid & 1;
  uint32 wv = 0;
#pragma unroll
  for (int t=0;t<2;++t){
#pragma unroll
    for (int r=0;r<16;++r){
      const int key = (r&3) + 8*(r>>2) + 4*h + 32*t;
      if (mask[b*NS + kt*64 + key] != 0) wv |= (1u << (r + 16*t));
    }
  }
  MW[tid] = wv;
}

// ---------------------------------------------------------------------------
// Split-bf16 GEMM via MFMA, global_load_lds staging + XOR-swizzled LDS.
// (unchanged from rounds 7/8)
// ---------------------------------------------------------------------------
template<int MODE, int NT>
__global__ __launch_bounds__(256)
void k_gemm(const ushort* __restrict__ Ah, const ushort* __restrict__ Al,
            const ushort* __restrict__ Bh, const ushort* __restrict__ Bl,
            float* __restrict__ C,
            ushort* __restrict__ Qo, ushort* __restrict__ Ko, ushort* __restrict__ Vo,
            int M, int N, int K)
{
  __shared__ ushort Ash[4096], Asl[4096], Bsh[4096];
  __shared__ ushort Bsl[NT == 3 ? 4096 : 16];
  const int tid = threadIdx.x;
  const int lane = tid & 63;
  const int w = tid >> 6;
  const int wm = w & 1, wn = w >> 1;
  const int l15 = lane & 15, lg = lane >> 4;
  const int m0 = blockIdx.y*128, n0 = blockIdx.x*128;

  f32x4 acc[4][4] = {};

  const int srow   = tid >> 2;
  const int schunk = tid & 3;
  const int ldst   = tid*8;

  for (int k0 = 0; k0 < K; k0 += 32) {
    if (k0) __syncthreads();
#pragma unroll
    for (int i=0;i<2;++i){
      const int row = i*64 + srow;
      const int kc  = (schunk ^ ((row>>1)&3))*8;
      const size_t ao = (size_t)(m0+row)*K + k0 + kc;
      const size_t bo = (size_t)(n0+row)*K + k0 + kc;
      gl_lds16(Ah+ao, &Ash[i*2048+ldst]);
      gl_lds16(Al+ao, &Asl[i*2048+ldst]);
      gl_lds16(Bh+bo, &Bsh[i*2048+ldst]);
      if (NT == 3) gl_lds16(Bl+bo, &Bsl[i*2048+ldst]);
    }
    __syncthreads();

    bf16x8 fah[4], fal[4], fbh[4], fbl[4];
#pragma unroll
    for (int i=0;i<4;++i){
      const int ra = wm*64 + i*16 + l15;
      const int ca = (lg ^ ((ra>>1)&3))*8;
      fah[i] = *(const bf16x8*)&Ash[ra*32 + ca];
      fal[i] = *(const bf16x8*)&Asl[ra*32 + ca];
      const int rb = wn*64 + i*16 + l15;
      const int cb = (lg ^ ((rb>>1)&3))*8;
      fbh[i] = *(const bf16x8*)&Bsh[rb*32 + cb];
      if (NT == 3) fbl[i] = *(const bf16x8*)&Bsl[rb*32 + cb];
    }
    __builtin_amdgcn_s_setprio(1);
#pragma unroll
    for (int mi=0;mi<4;++mi){
#pragma unroll
      for (int ni=0;ni<4;++ni){
        acc[mi][ni] = __builtin_amdgcn_mfma_f32_16x16x32_bf16(fah[mi], fbh[ni], acc[mi][ni], 0,0,0);
        if (NT == 3)
          acc[mi][ni] = __builtin_amdgcn_mfma_f32_16x16x32_bf16(fah[mi], fbl[ni], acc[mi][ni], 0,0,0);
        acc[mi][ni] = __builtin_amdgcn_mfma_f32_16x16x32_bf16(fal[mi], fbh[ni], acc[mi][ni], 0,0,0);
      }
    }
    __builtin_amdgcn_s_setprio(0);
  }

#pragma unroll
  for (int mi=0;mi<4;++mi){
#pragma unroll
    for (int ni=0;ni<4;++ni){
#pragma unroll
      for (int j=0;j<4;++j){
        const int m = m0 + wm*64 + mi*16 + (lane>>4)*4 + j;
        const int n = n0 + wn*64 + ni*16 + l15;
        const float v = acc[mi][ni][j];
        if (MODE == 0) {
          const int bb = m >> 11, ss = m & 2047;
          const int hh = n / 192, rr = n - hh*192;
          const int d = rr & 63;
          if (rr < 64) {
            Qo[((size_t)(bb*NH + hh)*NS + ss)*ND + d] = f2bf(v * QSCALE);
          } else if (rr < 128) {
            Ko[((size_t)(bb*NH + hh)*NS + ss)*ND + d] = f2bf(v);
          } else {
            Vo[((size_t)(bb*NH + hh)*ND + d)*NS + ss] = f2bf(v);  // V^T
          }
        } else {
          C[(size_t)m*N + n] = v;
        }
      }
    }
  }
}

// ---------------------------------------------------------------------------
// Flash attention, swapped-QK^T 32x32x16 MFMA, base-2 softmax, in-place P.
// __launch_bounds__(256,4): <=128 unified regs -> 4 waves/SIMD.
// exp2 via builtin (hazard-handled single v_exp_f32); __shfl_xor reductions;
// pointer-increment staging; 2x-unrolled double-buffer loop.
// ---------------------------------------------------------------------------
__global__ __launch_bounds__(256, 4)
void k_attn(const ushort* __restrict__ Qb, const ushort* __restrict__ Kb,
            const ushort* __restrict__ VTb, const uint32* __restrict__ MW,
            ushort* __restrict__ Ohi, ushort* __restrict__ Olo)
{
  __shared__ ushort Kls[2][4096];  // [buf][64 keys][64 d] swizzled
  __shared__ ushort Vls[2][4096];  // [buf][64 d][64 keys] swizzled

  const int tid = threadIdx.x;
  const int lane = tid & 63;
  const int w = tid >> 6;
  const int l31 = lane & 31;
  const int h = lane >> 5;
  const int lx = (l31 & 7) << 4;
  const int qt = blockIdx.x, head = blockIdx.y, b = blockIdx.z;
  const int bh = b*NH + head;
  const int qglob = qt*128 + w*32 + l31;

  bf16x8 qf[4];
  {
    const ushort* qp = Qb + ((size_t)bh*NS + qglob)*ND + h*8;
#pragma unroll
    for (int s=0;s<4;++s) qf[s] = *(const bf16x8*)(qp + s*16);
  }

  // staging pointers (advance per tile; global side pre-swizzled, LDS linear)
  const int srow = (w<<3) + (lane>>3);
  const int scol = ((lane&7) ^ (lane>>3)) << 3;
  const ushort* kp0 = Kb  + (size_t)bh*NS*ND + (size_t)srow*ND + scol;
  const ushort* kp1 = kp0 + 32*ND;
  const ushort* vp0 = VTb + (size_t)bh*ND*NS + (size_t)srow*NS + scol;
  const ushort* vp1 = vp0 + (size_t)32*NS;
  const uint32* mwp = MW + b*64 + h;
  const int lbase = (w<<9);

#define STAGE_TO(BUF)                                                         \
  {                                                                           \
    gl_lds16(kp0, &Kls[BUF][lbase]);                                          \
    gl_lds16(kp1, &Kls[BUF][2048 + lbase]);                                   \
    gl_lds16(vp0, &Vls[BUF][lbase]);                                          \
    gl_lds16(vp1, &Vls[BUF][2048 + lbase]);                                   \
    kp0 += 64*ND; kp1 += 64*ND; vp0 += 64; vp1 += 64;                         \
  }

  f32x16 o0, o1;
#pragma unroll
  for (int r=0;r<16;++r){ o0[r]=0.f; o1[r]=0.f; }
  float m_run = -INFINITY, l_run = 0.f;

#define ATTN_TILE(BUF)                                                        \
  {                                                                           \
    const uint32 mw = *mwp; mwp += 2;                                         \
    f32x16 z0, z1;                                                            \
    _Pragma("unroll")                                                         \
    for (int r=0;r<16;++r){ z0[r]=0.f; z1[r]=0.f; }                           \
    const char* kbase = (const char*)&Kls[BUF][0];                            \
    _Pragma("unroll")                                                         \
    for (int s=0;s<4;++s){                                                    \
      const int cb = (s*32 + h*16) ^ lx;                                      \
      bf16x8 kf0 = *(const bf16x8*)(kbase + l31*128 + cb);                    \
      z0 = __builtin_amdgcn_mfma_f32_32x32x16_bf16(kf0, qf[s], z0, 0,0,0);    \
      bf16x8 kf1 = *(const bf16x8*)(kbase + (32+l31)*128 + cb);               \
      z1 = __builtin_amdgcn_mfma_f32_32x32x16_bf16(kf1, qf[s], z1, 0,0,0);    \
    }                                                                         \
    _Pragma("unroll")                                                         \
    for (int r=0;r<16;++r){                                                   \
      z0[r] = (mw & (1u<<r))      ? z0[r] : -INFINITY;                        \
      z1[r] = (mw & (1u<<(16+r))) ? z1[r] : -INFINITY;                        \
    }                                                                         \
    float tmax = fmaxf(z0[0], z1[0]);                                         \
    _Pragma("unroll")                                                         \
    for (int r=1;r<16;++r) tmax = fmaxf(tmax, fmaxf(z0[r], z1[r]));           \
    tmax = fmaxf(tmax, __shfl_xor(tmax, 32));                                 \
    if (!__all(tmax <= m_run)) {                                              \
      const float mnew  = fmaxf(m_run, tmax);                                 \
      const float msafe = fmaxf(mnew, -1e30f);                                \
      const float alpha = exp2x(m_run - msafe);                               \
      m_run = mnew; l_run *= alpha;                                           \
      _Pragma("unroll")                                                       \
      for (int r=0;r<16;++r){ o0[r] *= alpha; o1[r] *= alpha; }               \
    }                                                                         \
    const float mbase = fmaxf(m_run, -1e30f);                                 \
    float psum = 0.f;                                                         \
    _Pragma("unroll")                                                         \
    for (int r=0;r<16;++r){                                                   \
      z0[r] = exp2x(z0[r] - mbase);                                           \
      z1[r] = exp2x(z1[r] - mbase);                                           \
      psum += z0[r] + z1[r];                                                  \
    }                                                                         \
    psum += __shfl_xor(psum, 32);                                             \
    l_run += psum;                                                            \
    const char* vbase = (const char*)&Vls[BUF][0];                            \
    _Pragma("unroll")                                                         \
    for (int ks=0;ks<4;++ks){                                                 \
      const f32x16& zz = (ks < 2) ? z0 : z1;                                  \
      const int rb = (ks&1)*8;                                                \
      uint32 d0 = cvtpk(zz[rb+0], zz[rb+1]);                                  \
      uint32 d2 = cvtpk(zz[rb+4], zz[rb+5]);                                  \
      pl32swap(d0, d2);                                                       \
      uint32 d1 = cvtpk(zz[rb+2], zz[rb+3]);                                  \
      uint32 d3 = cvtpk(zz[rb+6], zz[rb+7]);                                  \
      pl32swap(d1, d3);                                                       \
      union { uint32 u[4]; bf16x8 v; } pf;                                    \
      pf.u[0]=d0; pf.u[1]=d1; pf.u[2]=d2; pf.u[3]=d3;                         \
      const int cb = (ks*32 + h*16) ^ lx;                                     \
      bf16x8 vf0 = *(const bf16x8*)(vbase + l31*128 + cb);                    \
      o0 = __builtin_amdgcn_mfma_f32_32x32x16_bf16(vf0, pf.v, o0, 0,0,0);     \
      bf16x8 vf1 = *(const bf16x8*)(vbase + (32+l31)*128 + cb);               \
      o1 = __builtin_amdgcn_mfma_f32_32x32x16_bf16(vf1, pf.v, o1, 0,0,0);     \
    }                                                                         \
  }

  STAGE_TO(0);
  __syncthreads();

  for (int kt = 0; kt < NS/64; kt += 2){
    STAGE_TO(1);
    ATTN_TILE(0);
    __syncthreads();
    if (kt + 2 < NS/64) STAGE_TO(0);
    ATTN_TILE(1);
    __syncthreads();
  }

  const float inv = 1.f / l_run;
  const size_t obase = ((size_t)(b*NS + qglob))*NE + head*ND;
#pragma unroll
  for (int a=0;a<2;++a){
#pragma unroll
    for (int rp=0;rp<8;++rp){
      const int r = rp*2;
      const float v0 = (a ? o1[r]   : o0[r])   * inv;
      const float v1 = (a ? o1[r+1] : o0[r+1]) * inv;
      ushort h0,lo0,h1,lo1;
      split2(v0, h0, lo0); split2(v1, h1, lo1);
      const int d = (r&3) + 8*(r>>2) + 4*h + 32*a;
      *(uint32*)(Ohi + obase + d) = (uint32)h0 | ((uint32)h1<<16);
      *(uint32*)(Olo + obase + d) = (uint32)lo0 | ((uint32)lo1<<16);
    }
  }
#undef STAGE_TO
#undef ATTN_TILE
}

// ---------------------------------------------------------------------------
extern "C" void kernel_launch(void* const* d_in, const int* in_sizes, int n_in,
                              void* d_out, int out_size, void* d_ws, size_t ws_size,
                              hipStream_t stream)
{
  const float* X    = (const float*)d_in[0];
  const int*   mask = (const int*)d_in[1];
  const float* Wqkv = (const float*)d_in[2];
  const float* Wfc  = (const float*)d_in[3];
  float* out = (float*)d_out;

  char* p = (char*)d_ws;
  const size_t szXE = (size_t)NB*NS*NE;
  const size_t szT  = (size_t)BHN*NS*ND;
  ushort* Xhi = (ushort*)p; p += szXE*2;
  ushort* Xlo = (ushort*)p; p += szXE*2;
  ushort* Wqh = (ushort*)p; p += (size_t)NQKV*NE*2;
  ushort* Wql = (ushort*)p; p += (size_t)NQKV*NE*2;
  ushort* Wfh = (ushort*)p; p += (size_t)NE*NE*2;
  ushort* Wfl = (ushort*)p; p += (size_t)NE*NE*2;
  ushort* Qb  = (ushort*)p; p += szT*2;
  ushort* Kb  = (ushort*)p; p += szT*2;
  ushort* VTb = (ushort*)p; p += szT*2;
  ushort* Ohi = (ushort*)p; p += szXE*2;
  ushort* Olo = (ushort*)p; p += szXE*2;
  uint32* MW  = (uint32*)p; p += 256*4;

  k_convert_x<<<(int)(szXE/2048), 256, 0, stream>>>(X, Xhi, Xlo);
  k_transpose_w<<<dim3(NQKV/64, NE/64), 256, 0, stream>>>(Wqkv, Wqh, Wql, NE, NQKV);
  k_transpose_w<<<dim3(NE/64, NE/64), 256, 0, stream>>>(Wfc, Wfh, Wfl, NE, NE);
  k_maskprep<<<1, 256, 0, stream>>>(mask, MW);
  k_gemm<0,2><<<dim3(NQKV/128, (NB*NS)/128), 256, 0, stream>>>(
      Xhi, Xlo, Wqh, Wql, nullptr, Qb, Kb, VTb, NB*NS, NQKV, NE);
  k_attn<<<dim3(NS/128, NH, NB), 256, 0, stream>>>(Qb, Kb, VTb, MW, Ohi, Olo);
  k_gemm<1,3><<<dim3(NE/128, (NB*NS)/128), 256, 0, stream>>>(
      Ohi, Olo, Wfh, Wfl, out, nullptr, nullptr, nullptr, NB*NS, NE, NE);
}